// Round 1
// baseline (651.187 us; speedup 1.0000x reference)
//
#include <hip/hip_runtime.h>
#include <math.h>

// SharedLora on MI355X.
// Levels: K (NBINS) = {40,200,400,1000,2000,4000,8000}, rep = 8000/K.
// w[r,c,j] = sum_lvl ( wb_lvl[r0, idx_lvl(j)] + sum_a comp[a,c]*Wd_lvl[r0,a,idx_lvl(j)] )
// Restructured: U[a][j] = sum_lvl Wd_lvl[r0,a,idx_lvl(j)]  (level-sum BEFORE projection)
//               w[c][j] = bsum[j] + sum_a comp[a,c]*U[a][j]
// likelihood[i] = w_raw[...] - (log sum_j exp(w) + log 25)
// kl = count*(-(log1.5+0.5log2pi)) - (0.5/2.25)*sum wd^2   (quad computed exactly in k_kl)

#define NROI 256
#define NC 20
#define NFINAL 8000
#define NCUTS 500000

__global__ __launch_bounds__(256, 2) void k_w(
    const float* __restrict__ comp,
    const float* __restrict__ wb0, const float* __restrict__ wd0,
    const float* __restrict__ wb1, const float* __restrict__ wd1,
    const float* __restrict__ wb2, const float* __restrict__ wd2,
    const float* __restrict__ wb3, const float* __restrict__ wd3,
    const float* __restrict__ wb4, const float* __restrict__ wd4,
    const float* __restrict__ wb5, const float* __restrict__ wd5,
    const float* __restrict__ wb6, const float* __restrict__ wd6,
    const int* __restrict__ regions_oi,
    float* __restrict__ w_raw, float* __restrict__ s_part)
{
    __shared__ float csT[400];      // csT[c*20+a] = comp[a*20+c]
    __shared__ float wpart[4 * 20];
    const int tid = threadIdx.x;
    const int r = blockIdx.x >> 2;
    const int chunk = blockIdx.x & 3;
    for (int i = tid; i < 400; i += 256) csT[i] = comp[(i % 20) * 20 + (i / 20)];
    const int r0 = regions_oi[r];
    __syncthreads();

    const float* __restrict__ p6 = wd6 + (size_t)r0 * (20 * 8000);
    const float* __restrict__ p5 = wd5 + (size_t)r0 * (20 * 4000);
    const float* __restrict__ p4 = wd4 + (size_t)r0 * (20 * 2000);
    const float* __restrict__ p3 = wd3 + (size_t)r0 * (20 * 1000);
    const float* __restrict__ p2 = wd2 + (size_t)r0 * (20 * 400);
    const float* __restrict__ p1 = wd1 + (size_t)r0 * (20 * 200);
    const float* __restrict__ p0 = wd0 + (size_t)r0 * (20 * 40);
    const float* __restrict__ b6 = wb6 + (size_t)r0 * 8000;
    const float* __restrict__ b5 = wb5 + (size_t)r0 * 4000;
    const float* __restrict__ b4 = wb4 + (size_t)r0 * 2000;
    const float* __restrict__ b3 = wb3 + (size_t)r0 * 1000;
    const float* __restrict__ b2 = wb2 + (size_t)r0 * 400;
    const float* __restrict__ b1 = wb1 + (size_t)r0 * 200;
    const float* __restrict__ b0 = wb0 + (size_t)r0 * 40;

    float sexp[20];
#pragma unroll
    for (int c = 0; c < 20; c++) sexp[c] = 0.f;

    // 500 groups of 4 consecutive j per chunk of 2000 bins
    for (int g = tid; g < 500; g += 256) {
        const int jb = chunk * 2000 + g * 4;
        const int i5 = jb >> 1, i4 = jb >> 2, i3 = jb >> 3;
        const int i2 = jb / 20, i1 = jb / 40, i0 = jb / 200;

        float cu[20];
#pragma unroll
        for (int a = 0; a < 20; a++)
            cu[a] = p4[a * 2000 + i4] + p3[a * 1000 + i3] + p2[a * 400 + i2]
                  + p1[a * 200 + i1] + p0[a * 40 + i0];

        float u0[20], u1[20], u2[20], u3[20];
#pragma unroll
        for (int a = 0; a < 20; a++) {
            const float2 v5 = *(const float2*)(p5 + a * 4000 + i5);
            const float4 v6 = *(const float4*)(p6 + (size_t)a * 8000 + jb);
            const float c01 = cu[a] + v5.x;
            const float c23 = cu[a] + v5.y;
            u0[a] = c01 + v6.x; u1[a] = c01 + v6.y;
            u2[a] = c23 + v6.z; u3[a] = c23 + v6.w;
        }

        const float4 q6 = *(const float4*)(b6 + jb);
        const float2 q5 = *(const float2*)(b5 + i5);
        const float bc = b4[i4] + b3[i3] + b2[i2] + b1[i1] + b0[i0];
        const float bb0 = bc + q5.x + q6.x;
        const float bb1 = bc + q5.x + q6.y;
        const float bb2 = bc + q5.y + q6.z;
        const float bb3 = bc + q5.y + q6.w;

        float* wp = w_raw + ((size_t)r * 20) * 8000 + jb;
#pragma unroll
        for (int c = 0; c < 20; c++) {
            float a0 = bb0, a1 = bb1, a2 = bb2, a3 = bb3;
            const float* cr = &csT[c * 20];
#pragma unroll
            for (int a = 0; a < 20; a++) {
                const float cc = cr[a];
                a0 += cc * u0[a]; a1 += cc * u1[a];
                a2 += cc * u2[a]; a3 += cc * u3[a];
            }
            float4 o; o.x = a0; o.y = a1; o.z = a2; o.w = a3;
            *(float4*)(wp + (size_t)c * 8000) = o;
            // |w| is small (~<3): unnormalized exp-sum is safe in f32
            sexp[c] += __expf(a0) + __expf(a1) + __expf(a2) + __expf(a3);
        }
    }

    // block-reduce sexp[20] over 256 threads (4 waves)
#pragma unroll
    for (int c = 0; c < 20; c++) {
        float s = sexp[c];
#pragma unroll
        for (int off = 32; off > 0; off >>= 1) s += __shfl_down(s, off, 64);
        if ((tid & 63) == 0) wpart[(tid >> 6) * 20 + c] = s;
    }
    __syncthreads();
    if (tid < 20) {
        s_part[(size_t)blockIdx.x * 20 + tid] =
            wpart[tid] + wpart[20 + tid] + wpart[40 + tid] + wpart[60 + tid];
    }
}

__global__ void k_sub(const float* __restrict__ s_part, float* __restrict__ sub)
{
    const int i = blockIdx.x * 256 + threadIdx.x;
    if (i >= NROI * NC) return;
    const int r = i / 20, c = i % 20;
    float s = 0.f;
#pragma unroll
    for (int ch = 0; ch < 4; ch++) s += s_part[(size_t)(r * 4 + ch) * 20 + c];
    sub[i] = logf(s) + 3.2188758248682006f;   // + log(25)
}

__global__ void k_init(float* __restrict__ kl)
{
    // count = 256*20*15640 = 80,076,800 ; per-element const = -(log1.5 + 0.5*log(2pi))
    kl[0] = (float)(-80076800.0 * 1.3244036413128371);
}

__global__ __launch_bounds__(256, 2) void k_kl(
    const float* __restrict__ comp,
    const float* __restrict__ wd0, const float* __restrict__ wd1,
    const float* __restrict__ wd2, const float* __restrict__ wd3,
    const float* __restrict__ wd4, const float* __restrict__ wd5,
    const float* __restrict__ wd6,
    const int* __restrict__ regions_oi,
    float* __restrict__ kl_out)
{
    __shared__ float csT[400];
    __shared__ float wpart[4];
    const int tid = threadIdx.x;
    for (int i = tid; i < 400; i += 256) csT[i] = comp[(i % 20) * 20 + (i / 20)];
    const int r0 = regions_oi[blockIdx.y];
    __syncthreads();

    // column-groups of 4: per region 15640/4 = 3910 groups.
    // group offsets: L0 [0,10) L1 [10,60) L2 [60,160) L3 [160,410) L4 [410,910)
    //                L5 [910,1910) L6 [1910,3910)
    const int cg = blockIdx.x * 256 + tid;
    float q = 0.f;
    if (cg < 3910) {
        const float* wd; int K, k0;
        if (cg < 160) {
            if (cg < 10)      { wd = wd0; K = 40;   k0 = cg * 4; }
            else if (cg < 60) { wd = wd1; K = 200;  k0 = (cg - 10) * 4; }
            else              { wd = wd2; K = 400;  k0 = (cg - 60) * 4; }
        } else if (cg < 910) {
            if (cg < 410)     { wd = wd3; K = 1000; k0 = (cg - 160) * 4; }
            else              { wd = wd4; K = 2000; k0 = (cg - 410) * 4; }
        } else if (cg < 1910) { wd = wd5; K = 4000; k0 = (cg - 910) * 4; }
        else                  { wd = wd6; K = 8000; k0 = (cg - 1910) * 4; }

        const float* p = wd + (size_t)r0 * 20 * K + k0;
        float4 v[20];
#pragma unroll
        for (int a = 0; a < 20; a++) v[a] = *(const float4*)(p + (size_t)a * K);
#pragma unroll
        for (int c = 0; c < 20; c++) {
            float a0 = 0.f, a1 = 0.f, a2 = 0.f, a3 = 0.f;
            const float* cr = &csT[c * 20];
#pragma unroll
            for (int a = 0; a < 20; a++) {
                const float cc = cr[a];
                a0 += cc * v[a].x; a1 += cc * v[a].y;
                a2 += cc * v[a].z; a3 += cc * v[a].w;
            }
            q += a0 * a0 + a1 * a1 + a2 * a2 + a3 * a3;
        }
    }
#pragma unroll
    for (int off = 32; off > 0; off >>= 1) q += __shfl_down(q, off, 64);
    if ((tid & 63) == 0) wpart[tid >> 6] = q;
    __syncthreads();
    if (tid == 0) {
        const float s = wpart[0] + wpart[1] + wpart[2] + wpart[3];
        atomicAdd(kl_out, s * (-0.5f / 2.25f));
    }
}

__global__ void k_gather(const int* __restrict__ lri, const int* __restrict__ lci,
                         const int* __restrict__ cli, const int* __restrict__ coords,
                         const float* __restrict__ w_raw, const float* __restrict__ sub,
                         float* __restrict__ out)
{
    const int i = blockIdx.x * 256 + threadIdx.x;
    if (i >= NCUTS) return;
    const int r = lri[i];
    const int c = cli[lci[i]];
    int co = coords[i];
    co = co < 0 ? 0 : (co > 199999 ? 199999 : co);
    const int bin = co / 25;
    const int rc = r * 20 + c;
    out[i] = w_raw[(size_t)rc * 8000 + bin] - sub[rc];
}

extern "C" void kernel_launch(void* const* d_in, const int* in_sizes, int n_in,
                              void* d_out, int out_size, void* d_ws, size_t ws_size,
                              hipStream_t stream)
{
    const float* comp = (const float*)d_in[0];
    const float* wb[7];
    const float* wd[7];
    // setup_inputs dict order interleaves bias/delta per level; detect defensively.
    if (in_sizes[2] == 400000) {
        for (int l = 0; l < 7; l++) { wb[l] = (const float*)d_in[1 + 2 * l]; wd[l] = (const float*)d_in[2 + 2 * l]; }
    } else {
        for (int l = 0; l < 7; l++) { wb[l] = (const float*)d_in[1 + l]; wd[l] = (const float*)d_in[8 + l]; }
    }
    const int* regions_oi = (const int*)d_in[15];
    const int* lri   = (const int*)d_in[16];
    const int* lci   = (const int*)d_in[17];
    const int* cli   = (const int*)d_in[18];
    const int* coords= (const int*)d_in[19];
    float* out = (float*)d_out;

    float* w_raw  = (float*)d_ws;                         // 256*20*8000 f32 = 163.84 MB
    float* s_part = w_raw + (size_t)NROI * NC * NFINAL;   // 1024*20 f32
    float* sub    = s_part + 1024 * 20;                   // 5120 f32
    const size_t need = ((size_t)NROI * NC * NFINAL + 1024 * 20 + NROI * NC) * sizeof(float);
    if (ws_size < need) return;  // workspace too small: bail (visible as validation failure)

    k_init<<<1, 1, 0, stream>>>(out + NCUTS);
    k_w<<<1024, 256, 0, stream>>>(comp,
        wb[0], wd[0], wb[1], wd[1], wb[2], wd[2], wb[3], wd[3],
        wb[4], wd[4], wb[5], wd[5], wb[6], wd[6],
        regions_oi, w_raw, s_part);
    k_sub<<<(NROI * NC + 255) / 256, 256, 0, stream>>>(s_part, sub);
    k_kl<<<dim3(16, 256), 256, 0, stream>>>(comp,
        wd[0], wd[1], wd[2], wd[3], wd[4], wd[5], wd[6],
        regions_oi, out + NCUTS);
    k_gather<<<(NCUTS + 255) / 256, 256, 0, stream>>>(lri, lci, cli, coords, w_raw, sub, out);
}

// Round 2
// 245.773 us; speedup vs baseline: 2.6495x; 2.6495x over previous
//
#include <hip/hip_runtime.h>
#include <math.h>

// SharedLora on MI355X — round 2.
// v1 failed on register spills in k_w (per-thread u[20]x4 arrays -> scratch,
// +870 MB of spill traffic). v2 stages the level-summed U[20][500] tile in LDS:
//   phase 1: U[a][j] = sum_lvl Wd_lvl[r0,a,idx_lvl(j)]  -> LDS (40 KB)
//            bias[j] = sum_lvl wb_lvl[r0,idx_lvl(j)]    -> LDS (2 KB)
//   phase 2: w[c][j] = bias[j] + sum_a comp[a,c]*U[a][j]; store + exp-sum.
// Per-thread state is a float4 accumulator -> no spills, VGPR ~64.

#define NROI 256
#define NC 20
#define NFINAL 8000
#define NCUTS 500000
#define TILE 500            // bins per block; 16 tiles per region
#define UPAD 504            // padded LDS row stride (floats)

__global__ __launch_bounds__(256, 3) void k_w(
    const float* __restrict__ comp,
    const float* __restrict__ wb0, const float* __restrict__ wd0,
    const float* __restrict__ wb1, const float* __restrict__ wd1,
    const float* __restrict__ wb2, const float* __restrict__ wd2,
    const float* __restrict__ wb3, const float* __restrict__ wd3,
    const float* __restrict__ wb4, const float* __restrict__ wd4,
    const float* __restrict__ wb5, const float* __restrict__ wd5,
    const float* __restrict__ wb6, const float* __restrict__ wd6,
    const int* __restrict__ regions_oi,
    float* __restrict__ w_raw, float* __restrict__ s_part)
{
    __shared__ float U_sh[20 * UPAD];   // 40320 B
    __shared__ float bias_sh[TILE];     // 2000 B
    __shared__ float csT[400];          // csT[c*20+a] = comp[a*20+c]
    __shared__ float sexp_sh[20];

    const int tid = threadIdx.x;
    const int r = blockIdx.x >> 4;
    const int tile = blockIdx.x & 15;
    const int base = tile * TILE;

    for (int i = tid; i < 400; i += 256) csT[i] = comp[(i % 20) * 20 + (i / 20)];
    if (tid < 20) sexp_sh[tid] = 0.f;
    const int r0 = regions_oi[r];

    const float* __restrict__ p6 = wd6 + (size_t)r0 * (20 * 8000);
    const float* __restrict__ p5 = wd5 + (size_t)r0 * (20 * 4000);
    const float* __restrict__ p4 = wd4 + (size_t)r0 * (20 * 2000);
    const float* __restrict__ p3 = wd3 + (size_t)r0 * (20 * 1000);
    const float* __restrict__ p2 = wd2 + (size_t)r0 * (20 * 400);
    const float* __restrict__ p1 = wd1 + (size_t)r0 * (20 * 200);
    const float* __restrict__ p0 = wd0 + (size_t)r0 * (20 * 40);
    const float* __restrict__ b6 = wb6 + (size_t)r0 * 8000;
    const float* __restrict__ b5 = wb5 + (size_t)r0 * 4000;
    const float* __restrict__ b4 = wb4 + (size_t)r0 * 2000;
    const float* __restrict__ b3 = wb3 + (size_t)r0 * 1000;
    const float* __restrict__ b2 = wb2 + (size_t)r0 * 400;
    const float* __restrict__ b1 = wb1 + (size_t)r0 * 200;
    const float* __restrict__ b0 = wb0 + (size_t)r0 * 40;

    // ---- phase 1: fill U_sh (2500 float4 groups) + bias_sh (125 groups) ----
    // j is a multiple of 4 everywhere, so all the coarse-level indices
    // (j>>2, j>>3, j/20, j/40, j/200) are constant within a 4-group.
#pragma unroll 1
    for (int k = 0; k < 11; k++) {
        const int g = tid + k * 256;
        if (g >= 2625) break;
        if (g < 2500) {
            const int a = g / 125;
            const int jg = g - a * 125;
            const int j = base + jg * 4;
            const float4 v6 = *(const float4*)(p6 + (size_t)a * 8000 + j);
            const float2 v5 = *(const float2*)(p5 + a * 4000 + (j >> 1));
            const float sc = p4[a * 2000 + (j >> 2)] + p3[a * 1000 + (j >> 3)]
                           + p2[a * 400 + j / 20] + p1[a * 200 + j / 40]
                           + p0[a * 40 + j / 200];
            const float c01 = sc + v5.x, c23 = sc + v5.y;
            float4 u;
            u.x = c01 + v6.x; u.y = c01 + v6.y;
            u.z = c23 + v6.z; u.w = c23 + v6.w;
            *(float4*)(&U_sh[a * UPAD + jg * 4]) = u;
        } else {
            const int jg = g - 2500;
            const int j = base + jg * 4;
            const float4 v6 = *(const float4*)(b6 + j);
            const float2 v5 = *(const float2*)(b5 + (j >> 1));
            const float sc = b4[j >> 2] + b3[j >> 3] + b2[j / 20]
                           + b1[j / 40] + b0[j / 200];
            const float c01 = sc + v5.x, c23 = sc + v5.y;
            float4 u;
            u.x = c01 + v6.x; u.y = c01 + v6.y;
            u.z = c23 + v6.z; u.w = c23 + v6.w;
            *(float4*)(&bias_sh[jg * 4]) = u;
        }
    }
    __syncthreads();

    // ---- phase 2: w[c][j] = bias[j] + sum_a csT[c][a]*U[a][j] ----
#pragma unroll 1
    for (int k = 0; k < 10; k++) {
        const int g = tid + k * 256;
        if (g >= 2500) break;
        const int c = g / 125;
        const int jg = g - c * 125;
        float4 acc = *(const float4*)(&bias_sh[jg * 4]);
        const float* cr = &csT[c * 20];
#pragma unroll
        for (int a = 0; a < 20; a++) {
            const float cc = cr[a];
            const float4 u = *(const float4*)(&U_sh[a * UPAD + jg * 4]);
            acc.x += cc * u.x; acc.y += cc * u.y;
            acc.z += cc * u.z; acc.w += cc * u.w;
        }
        *(float4*)(w_raw + ((size_t)(r * 20 + c)) * 8000 + base + jg * 4) = acc;
        // |w| stays small (~<4): unnormalized exp-sum is safe in f32
        const float es = __expf(acc.x) + __expf(acc.y) + __expf(acc.z) + __expf(acc.w);
        atomicAdd(&sexp_sh[c], es);
    }
    __syncthreads();
    if (tid < 20) s_part[(size_t)blockIdx.x * 20 + tid] = sexp_sh[tid];
}

__global__ void k_sub(const float* __restrict__ s_part, float* __restrict__ sub)
{
    const int i = blockIdx.x * 256 + threadIdx.x;
    if (i >= NROI * NC) return;
    const int r = i / 20, c = i % 20;
    float s = 0.f;
#pragma unroll
    for (int t = 0; t < 16; t++) s += s_part[(size_t)(r * 16 + t) * 20 + c];
    sub[i] = logf(s) + 3.2188758248682006f;   // + log(25)
}

__global__ void k_init(float* __restrict__ kl)
{
    // count = 256*20*15640 = 80,076,800 ; per-element const = -(log1.5 + 0.5*log(2pi))
    kl[0] = (float)(-80076800.0 * 1.3244036413128371);
}

__global__ __launch_bounds__(256, 2) void k_kl(
    const float* __restrict__ comp,
    const float* __restrict__ wd0, const float* __restrict__ wd1,
    const float* __restrict__ wd2, const float* __restrict__ wd3,
    const float* __restrict__ wd4, const float* __restrict__ wd5,
    const float* __restrict__ wd6,
    const int* __restrict__ regions_oi,
    float* __restrict__ kl_out)
{
    __shared__ float csT[400];
    __shared__ float wpart[4];
    const int tid = threadIdx.x;
    for (int i = tid; i < 400; i += 256) csT[i] = comp[(i % 20) * 20 + (i / 20)];
    const int r0 = regions_oi[blockIdx.y];
    __syncthreads();

    // column-groups of 4: per region 15640/4 = 3910 groups.
    const int cg = blockIdx.x * 256 + tid;
    float q = 0.f;
    if (cg < 3910) {
        const float* wd; int K, k0;
        if (cg < 160) {
            if (cg < 10)      { wd = wd0; K = 40;   k0 = cg * 4; }
            else if (cg < 60) { wd = wd1; K = 200;  k0 = (cg - 10) * 4; }
            else              { wd = wd2; K = 400;  k0 = (cg - 60) * 4; }
        } else if (cg < 910) {
            if (cg < 410)     { wd = wd3; K = 1000; k0 = (cg - 160) * 4; }
            else              { wd = wd4; K = 2000; k0 = (cg - 410) * 4; }
        } else if (cg < 1910) { wd = wd5; K = 4000; k0 = (cg - 910) * 4; }
        else                  { wd = wd6; K = 8000; k0 = (cg - 1910) * 4; }

        const float* p = wd + (size_t)r0 * 20 * K + k0;
        float4 v[20];
#pragma unroll
        for (int a = 0; a < 20; a++) v[a] = *(const float4*)(p + (size_t)a * K);
#pragma unroll
        for (int c = 0; c < 20; c++) {
            float a0 = 0.f, a1 = 0.f, a2 = 0.f, a3 = 0.f;
            const float* cr = &csT[c * 20];
#pragma unroll
            for (int a = 0; a < 20; a++) {
                const float cc = cr[a];
                a0 += cc * v[a].x; a1 += cc * v[a].y;
                a2 += cc * v[a].z; a3 += cc * v[a].w;
            }
            q += a0 * a0 + a1 * a1 + a2 * a2 + a3 * a3;
        }
    }
#pragma unroll
    for (int off = 32; off > 0; off >>= 1) q += __shfl_down(q, off, 64);
    if ((tid & 63) == 0) wpart[tid >> 6] = q;
    __syncthreads();
    if (tid == 0) {
        const float s = wpart[0] + wpart[1] + wpart[2] + wpart[3];
        atomicAdd(kl_out, s * (-0.5f / 2.25f));
    }
}

__global__ void k_gather(const int* __restrict__ lri, const int* __restrict__ lci,
                         const int* __restrict__ cli, const int* __restrict__ coords,
                         const float* __restrict__ w_raw, const float* __restrict__ sub,
                         float* __restrict__ out)
{
    const int i = blockIdx.x * 256 + threadIdx.x;
    if (i >= NCUTS) return;
    const int r = lri[i];
    const int c = cli[lci[i]];
    int co = coords[i];
    co = co < 0 ? 0 : (co > 199999 ? 199999 : co);
    const int bin = co / 25;
    const int rc = r * 20 + c;
    out[i] = w_raw[(size_t)rc * 8000 + bin] - sub[rc];
}

extern "C" void kernel_launch(void* const* d_in, const int* in_sizes, int n_in,
                              void* d_out, int out_size, void* d_ws, size_t ws_size,
                              hipStream_t stream)
{
    const float* comp = (const float*)d_in[0];
    const float* wb[7];
    const float* wd[7];
    // setup_inputs dict order interleaves bias/delta per level; detect defensively.
    if (in_sizes[2] == 400000) {
        for (int l = 0; l < 7; l++) { wb[l] = (const float*)d_in[1 + 2 * l]; wd[l] = (const float*)d_in[2 + 2 * l]; }
    } else {
        for (int l = 0; l < 7; l++) { wb[l] = (const float*)d_in[1 + l]; wd[l] = (const float*)d_in[8 + l]; }
    }
    const int* regions_oi = (const int*)d_in[15];
    const int* lri   = (const int*)d_in[16];
    const int* lci   = (const int*)d_in[17];
    const int* cli   = (const int*)d_in[18];
    const int* coords= (const int*)d_in[19];
    float* out = (float*)d_out;

    float* w_raw  = (float*)d_ws;                         // 256*20*8000 f32 = 163.84 MB
    float* s_part = w_raw + (size_t)NROI * NC * NFINAL;   // 4096*20 f32
    float* sub    = s_part + 4096 * 20;                   // 5120 f32
    const size_t need = ((size_t)NROI * NC * NFINAL + 4096 * 20 + NROI * NC) * sizeof(float);
    if (ws_size < need) return;

    k_init<<<1, 1, 0, stream>>>(out + NCUTS);
    k_w<<<NROI * 16, 256, 0, stream>>>(comp,
        wb[0], wd[0], wb[1], wd[1], wb[2], wd[2], wb[3], wd[3],
        wb[4], wd[4], wb[5], wd[5], wb[6], wd[6],
        regions_oi, w_raw, s_part);
    k_sub<<<(NROI * NC + 255) / 256, 256, 0, stream>>>(s_part, sub);
    k_kl<<<dim3(16, 256), 256, 0, stream>>>(comp,
        wd[0], wd[1], wd[2], wd[3], wd[4], wd[5], wd[6],
        regions_oi, out + NCUTS);
    k_gather<<<(NCUTS + 255) / 256, 256, 0, stream>>>(lri, lci, cli, coords, w_raw, sub, out);
}